// Round 13
// baseline (368.753 us; speedup 1.0000x reference)
//
#include <hip/hip_runtime.h>
#include <hip/hip_fp8.h>
#include <math.h>

#define N_NODES 100000
#define N_EDGES 1600000
#define F_IN    4
#define HID     128
#define N_CLS   5
#define N_GRAPH 256
#define POOL_SEG 8

#define BSHIFT   9
#define BSIZE    512
#define NBUK     196            // ceil(100000 / 512)
#define NCHUNK   200
#define CHUNK    8000           // 200 * 8000 = 1.6M exactly
#define NBIN     8

typedef _Float16 f16;
typedef _Float16 f16x2 __attribute__((ext_vector_type(2)));
typedef _Float16 f16x8 __attribute__((ext_vector_type(8)));
typedef float f32x4 __attribute__((ext_vector_type(4)));

// decode 4-byte edge record: [src:17 | coef-f16-positive:15]; record 0 == dummy (src 0, coef 0)
__device__ __forceinline__ float rec_coef(unsigned r) {
    return (float)__builtin_bit_cast(_Float16, (unsigned short)(r & 0x7FFFu));
}

__device__ __forceinline__ float2 fp8x2_to_f32x2(unsigned short raw) {
    __hip_fp8x2_e4m3 t;
    t.__x = raw;
    return static_cast<float2>(t);
}

// 8 fp8 values (uint2) -> fma into acc[0..7] with coefficient c
__device__ __forceinline__ void fma8(float c, uint2 v, float* acc) {
    float2 p0 = fp8x2_to_f32x2((unsigned short)(v.x & 0xFFFFu));
    float2 p1 = fp8x2_to_f32x2((unsigned short)(v.x >> 16));
    float2 p2 = fp8x2_to_f32x2((unsigned short)(v.y & 0xFFFFu));
    float2 p3 = fp8x2_to_f32x2((unsigned short)(v.y >> 16));
    acc[0] = fmaf(c, p0.x, acc[0]); acc[1] = fmaf(c, p0.y, acc[1]);
    acc[2] = fmaf(c, p1.x, acc[2]); acc[3] = fmaf(c, p1.y, acc[3]);
    acc[4] = fmaf(c, p2.x, acc[4]); acc[5] = fmaf(c, p2.y, acc[5]);
    acc[6] = fmaf(c, p3.x, acc[6]); acc[7] = fmaf(c, p3.y, acc[7]);
}

// ---------------- CSR build step 1: per-(chunk,bucket) counts via LDS histogram -------------
__global__ __launch_bounds__(256) void k_bc(const int* __restrict__ dst, int* __restrict__ C) {
    __shared__ int cnt[NBUK];
    int t = threadIdx.x;
    if (t < NBUK) cnt[t] = 0;
    __syncthreads();
    int base = blockIdx.x * CHUNK;
#pragma unroll
    for (int it = 0; it < 32; ++it) {
        int idx = it * 256 + t;
        if (idx < CHUNK) atomicAdd(&cnt[dst[base + idx] >> BSHIFT], 1);
    }
    __syncthreads();
    if (t < NBUK) C[blockIdx.x * NBUK + t] = cnt[t];
}

// ---------------- step 2: offsets. Off[c][b] = prefix over chunks; bbase = bucket bases -----
__global__ __launch_bounds__(256) void k_bscan(const int* __restrict__ C, int* __restrict__ Off,
                                               int* __restrict__ bbase) {
    __shared__ int s[256];
    int b = threadIdx.x;
    int tot = 0;
    if (b < NBUK) {
        for (int c = 0; c < NCHUNK; ++c) {
            Off[c * NBUK + b] = tot;
            tot += C[c * NBUK + b];
        }
    }
    s[b] = (b < NBUK) ? tot : 0;
    __syncthreads();
    for (int off = 1; off < 256; off <<= 1) {
        int v = (b >= off) ? s[b - off] : 0;
        __syncthreads();
        s[b] += v;
        __syncthreads();
    }
    if (b < NBUK) bbase[b] = s[b] - tot;   // exclusive
    if (b == 0) bbase[NBUK] = N_EDGES;
}

// ---------------- step 3: scatter packed records into bucket-grouped array ------------------
// record: (src:17)<<9 | (dst & 511)
__global__ __launch_bounds__(256) void k_scatter(const int* __restrict__ src, const int* __restrict__ dst,
                                                 const int* __restrict__ Off, const int* __restrict__ bbase,
                                                 unsigned* __restrict__ bkt) {
    __shared__ int cur[NBUK];
    int t = threadIdx.x;
    if (t < NBUK) cur[t] = bbase[t] + Off[blockIdx.x * NBUK + t];
    __syncthreads();
    int base = blockIdx.x * CHUNK;
#pragma unroll
    for (int it = 0; it < 32; ++it) {
        int idx = it * 256 + t;
        if (idx < CHUNK) {
            int s = src[base + idx], d = dst[base + idx];
            int b = d >> BSHIFT;
            int p = atomicAdd(&cur[b], 1);
            bkt[p] = ((unsigned)s << BSHIFT) | (unsigned)(d & (BSIZE - 1));
        }
    }
}

// ---------------- step 4: per-bucket degree hist -> deg, dinv, padded total, bin counts -----
__global__ __launch_bounds__(256) void k_hist2(const unsigned* __restrict__ bkt,
                                               const int* __restrict__ bbase,
                                               int* __restrict__ deg, float* __restrict__ dinv,
                                               int* __restrict__ padTot, int* __restrict__ binCnt) {
    __shared__ int hist[BSIZE];
    __shared__ int tot;
    __shared__ int bc[NBIN];
    int t = threadIdx.x, b = blockIdx.x;
    hist[t] = 0; hist[t + 256] = 0;
    if (t == 0) tot = 0;
    if (t < NBIN) bc[t] = 0;
    __syncthreads();
    int s0 = bbase[b], s1 = bbase[b + 1];
    for (int e = s0 + t; e < s1; e += 256) atomicAdd(&hist[bkt[e] & (BSIZE - 1)], 1);
    __syncthreads();
    int loc = 0;
#pragma unroll
    for (int h = 0; h < 2; ++h) {
        int l = t + h * 256;
        int node = b * BSIZE + l;
        int d = hist[l];
        if (node < N_NODES) {
            deg[node] = d;
            dinv[node] = rsqrtf((float)d + 1.0f);
            int bin = (d + 15) >> 4;
            if (bin > NBIN - 1) bin = NBIN - 1;
            atomicAdd(&bc[bin], 1);
            loc += (d + 15) >> 4;
        }
    }
    atomicAdd(&tot, loc);
    __syncthreads();
    if (t == 0) padTot[b] = tot << 4;
    if (t < NBIN) binCnt[t * NBUK + b] = bc[t];   // bin-major layout
}

// ---------------- step 5: scan padded totals -> padded bases; scan bin table -> bin offsets -
__global__ __launch_bounds__(256) void k_pscan(const int* __restrict__ padTot, int* __restrict__ padBase,
                                               int* __restrict__ rowptrP,
                                               const int* __restrict__ binCnt, int* __restrict__ binOff) {
    __shared__ int s[256];
    __shared__ int s2[256];
    int b = threadIdx.x;
    int v = (b < NBUK) ? padTot[b] : 0;
    s[b] = v;
    __syncthreads();
    for (int off = 1; off < 256; off <<= 1) {
        int u = (b >= off) ? s[b - off] : 0;
        __syncthreads();
        s[b] += u;
        __syncthreads();
    }
    if (b < NBUK) padBase[b] = s[b] - v;
    if (b == 0) {
        padBase[NBUK] = s[NBUK - 1];
        rowptrP[N_NODES] = s[NBUK - 1];
    }
    // ---- scan the 8*196 bin table (7 elements per thread) ----
    int loc[7];
    int sum = 0;
    int base = b * 7;
#pragma unroll
    for (int j = 0; j < 7; ++j) {
        int idx = base + j;
        int u = (idx < NBIN * NBUK) ? binCnt[idx] : 0;
        loc[j] = sum; sum += u;
    }
    s2[b] = sum;
    __syncthreads();
    for (int off = 1; off < 256; off <<= 1) {
        int u = (b >= off) ? s2[b - off] : 0;
        __syncthreads();
        s2[b] += u;
        __syncthreads();
    }
    int excl = s2[b] - sum;
#pragma unroll
    for (int j = 0; j < 7; ++j) {
        int idx = base + j;
        if (idx < NBIN * NBUK) binOff[idx] = excl + loc[j];
    }
}

// ---------------- step 5b: scatter node ids into degree-binned order ------------------------
__global__ __launch_bounds__(256) void k_order(const int* __restrict__ deg,
                                               const int* __restrict__ binOff,
                                               int* __restrict__ order) {
    __shared__ int cur[NBIN];
    int t = threadIdx.x, b = blockIdx.x;
    if (t < NBIN) cur[t] = binOff[t * NBUK + b];
    __syncthreads();
#pragma unroll
    for (int h = 0; h < 2; ++h) {
        int node = b * BSIZE + t + h * 256;
        if (node < N_NODES) {
            int bin = (deg[node] + 15) >> 4;
            if (bin > NBIN - 1) bin = NBIN - 1;
            int p = atomicAdd(&cur[bin], 1);
            order[p] = node;
        }
    }
}

// ---------------- step 6: per-bucket padded CSR + coef fused; dummy slots = record 0 --------
__global__ __launch_bounds__(256) void k_local2(const unsigned* __restrict__ bkt,
                                                const int* __restrict__ bbase,
                                                const int* __restrict__ deg,
                                                const float* __restrict__ dinv,
                                                const int* __restrict__ padBase,
                                                int* __restrict__ rowptrP,
                                                unsigned* __restrict__ edges) {
    __shared__ int sc[BSIZE];
    __shared__ int cur[BSIZE];
    __shared__ float dv[BSIZE];
    int t = threadIdx.x, b = blockIdx.x;
    int base = padBase[b];
    int n0 = b * BSIZE + t, n1 = n0 + 256;
    int d0 = (n0 < N_NODES) ? deg[n0] : 0;
    int d1 = (n1 < N_NODES) ? deg[n1] : 0;
    int p0 = ((d0 + 15) >> 4) << 4;
    int p1 = ((d1 + 15) >> 4) << 4;
    sc[t] = p0; sc[t + 256] = p1;
    dv[t] = (n0 < N_NODES) ? dinv[n0] : 0.f;
    dv[t + 256] = (n1 < N_NODES) ? dinv[n1] : 0.f;
    __syncthreads();
    for (int off = 1; off < BSIZE; off <<= 1) {
        int i0 = t, i1 = t + 256;
        int v0 = (i0 >= off) ? sc[i0 - off] : 0;
        int v1 = (i1 >= off) ? sc[i1 - off] : 0;
        __syncthreads();
        sc[i0] += v0; sc[i1] += v1;
        __syncthreads();
    }
    int off0 = base + sc[t] - p0;
    int off1 = base + sc[t + 256] - p1;
    if (n0 < N_NODES) rowptrP[n0] = off0;
    if (n1 < N_NODES) rowptrP[n1] = off1;
    cur[t] = off0; cur[t + 256] = off1;
    int padT = sc[BSIZE - 1];
    // init padded region to dummy (record 0 = src 0, coef 0)
    for (int i = base + t; i < base + padT; i += 256) edges[i] = 0;
    __syncthreads();
    int s0 = bbase[b], s1 = bbase[b + 1];
    for (int e = s0 + t; e < s1; e += 256) {
        unsigned r = bkt[e];
        int dl = (int)(r & (BSIZE - 1));
        int s = (int)(r >> BSHIFT);
        int p = atomicAdd(&cur[dl], 1);
        float c = dv[dl] * dinv[s];
        unsigned short cb = __builtin_bit_cast(unsigned short, (f16)c);
        edges[p] = ((unsigned)s << 15) | (unsigned)(cb & 0x7FFFu);
    }
}

// ---------------- FUSED layer 1: wave-parallel Agg(x) + (Nx4)@(4x128) GEMM, fp8 out ---------
// Degree-ordered: group grp handles node order[blockIdx*16+grp] (balanced within block).
__global__ __launch_bounds__(256) void k_aggx1(const float4* __restrict__ x,
                                               const int* __restrict__ rowptrP,
                                               const unsigned* __restrict__ edges,
                                               const float* __restrict__ dinv,
                                               const int* __restrict__ order,
                                               const float* __restrict__ W1, const float* __restrict__ b1,
                                               unsigned* __restrict__ hA) {
    __shared__ float4 sxa[16];
    __shared__ int sni[16];
    __shared__ float sW[4 * HID];
    __shared__ float sb[HID];
    int t = threadIdx.x;
    sW[t] = W1[t];
    sW[t + 256] = W1[t + 256];
    if (t < HID) sb[t] = b1[t];
    int grp = t >> 4;             // 0..15 local node
    int l = t & 15;
    int node = order[blockIdx.x * 16 + grp];   // grid 6250 -> exact
    int beg = rowptrP[node], end = rowptrP[node + 1];
    float ax = 0.f, ay = 0.f, az = 0.f, aw = 0.f;
    for (int e = beg + l; e < end; e += 16) {
        unsigned r = edges[e];
        float c = rec_coef(r);
        float4 v = x[r >> 15];
        ax = fmaf(c, v.x, ax); ay = fmaf(c, v.y, ay);
        az = fmaf(c, v.z, az); aw = fmaf(c, v.w, aw);
    }
#pragma unroll
    for (int off = 1; off < 16; off <<= 1) {
        ax += __shfl_xor(ax, off, 64);
        ay += __shfl_xor(ay, off, 64);
        az += __shfl_xor(az, off, 64);
        aw += __shfl_xor(aw, off, 64);
    }
    if (l == 0) {
        float di = dinv[node];
        float c0 = di * di;
        float4 xv = x[node];
        sxa[grp] = make_float4(fmaf(c0, xv.x, ax), fmaf(c0, xv.y, ay),
                               fmaf(c0, xv.z, az), fmaf(c0, xv.w, aw));
        sni[grp] = node;
    }
    __syncthreads();

#pragma unroll
    for (int it = 0; it < 2; ++it) {
        int id = it * 256 + t;       // 512 units = 16 nodes x 32 col-groups
        int n = id >> 5;
        int g = id & 31;
        float4 a = sxa[n];
        float c[4];
#pragma unroll
        for (int j = 0; j < 4; ++j) {
            int col = g * 4 + j;
            float v = sb[col];
            v = fmaf(a.x, sW[col],           v);
            v = fmaf(a.y, sW[HID + col],     v);
            v = fmaf(a.z, sW[2 * HID + col], v);
            v = fmaf(a.w, sW[3 * HID + col], v);
            c[j] = fmaxf(v, 0.0f);
        }
        unsigned lo = __hip_fp8x2_e4m3(make_float2(c[0], c[1])).__x;
        unsigned hi = __hip_fp8x2_e4m3(make_float2(c[2], c[3])).__x;
        hA[sni[n] * 32 + g] = lo | (hi << 16);
    }
}

// ---------------- FUSED layers 2..4: Agg (fp8, wave/node, degree-ordered) -> LDS -> MFMA ----
// Block = 1024 thr = 16 waves = 16 nodes of (near-)equal padded degree -> barrier costs ~0.
template <bool FP8OUT>
__global__ __launch_bounds__(1024, 8) void k_aggemm8(const unsigned* __restrict__ h8,
                                                     const int* __restrict__ rowptrP,
                                                     const unsigned* __restrict__ edges,
                                                     const float* __restrict__ dinv,
                                                     const int* __restrict__ order,
                                                     const f16* __restrict__ Wp,
                                                     const float* __restrict__ bias,
                                                     void* __restrict__ outv) {
    __shared__ f16 S[16 * HID];   // 4 KB, rows XOR-swizzled at dword granularity
    __shared__ int sn[16];
    int wave = threadIdx.x >> 6;        // local strip row 0..15
    int lane = threadIdx.x & 63;
    int node0 = blockIdx.x * 16;
    int node = order[node0 + wave];
    int g = lane >> 4;
    int l = lane & 15;
    int beg = rowptrP[node], end = rowptrP[node + 1];
    const char* hp = (const char*)h8 + l * 8;

    if (lane == 0) sn[wave] = node;

    float acc[8];
    {
        float di = dinv[node];
        float c0 = (g == 0) ? di * di : 0.0f;
        uint2 v = *(const uint2*)(hp + ((size_t)node << 7));
        float2 p0 = fp8x2_to_f32x2((unsigned short)(v.x & 0xFFFFu));
        float2 p1 = fp8x2_to_f32x2((unsigned short)(v.x >> 16));
        float2 p2 = fp8x2_to_f32x2((unsigned short)(v.y & 0xFFFFu));
        float2 p3 = fp8x2_to_f32x2((unsigned short)(v.y >> 16));
        acc[0] = c0 * p0.x; acc[1] = c0 * p0.y;
        acc[2] = c0 * p1.x; acc[3] = c0 * p1.y;
        acc[4] = c0 * p2.x; acc[5] = c0 * p2.y;
        acc[6] = c0 * p3.x; acc[7] = c0 * p3.y;
    }

    for (int e = beg; e < end; e += 16) {
        unsigned rec16 = edges[e + l];
#pragma unroll
        for (int i = 0; i < 4; ++i) {
            unsigned rec = __shfl(rec16, i * 4 + g, 64);
            float c = rec_coef(rec);
            uint2 v = *(const uint2*)(hp + ((rec >> 8) & 0xFFFFFF80u));
            fma8(c, v, acc);
        }
    }

#pragma unroll
    for (int j = 0; j < 8; ++j) {
        acc[j] += __shfl_xor(acc[j], 16, 64);
        acc[j] += __shfl_xor(acc[j], 32, 64);
    }
    if (lane < 16) {
        f16x8 o;
#pragma unroll
        for (int j = 0; j < 8; ++j) o[j] = (f16)acc[j];
        int dw = (l * 4) ^ ((wave & 7) << 2);       // dword offset within row, swizzled
        *(f16x8*)&S[wave * HID + dw * 2] = o;
    }
    __syncthreads();

    // GEMM phase: waves 0..7 each handle column tile t = wave
    if (wave < 8) {
        int t = wave;
        int m = lane & 15;
        int q = lane >> 4;
        f32x4 c4 = (f32x4){0.f, 0.f, 0.f, 0.f};
#pragma unroll
        for (int ks = 0; ks < 4; ++ks) {
            int dw = (ks * 16 + q * 4) ^ ((m & 7) << 2);
            f16x8 a = *(const f16x8*)&S[m * HID + dw * 2];
            f16x8 b = *(const f16x8*)(Wp + ((size_t)(t * 4 + ks) * 64 + lane) * 8);
            c4 = __builtin_amdgcn_mfma_f32_16x16x32_f16(a, b, c4, 0, 0, 0);
        }
        float bb = bias[t * 16 + m];
#pragma unroll
        for (int r = 0; r < 4; ++r) {
            float val = fmaxf(c4[r] + bb, 0.0f);
            int row = sn[q * 4 + r];
            if constexpr (FP8OUT) {
                ((__hip_fp8_e4m3*)outv)[(size_t)row * HID + t * 16 + m] = __hip_fp8_e4m3(val);
            } else {
                ((f16*)outv)[(size_t)row * HID + t * 16 + m] = (f16)val;
            }
        }
    }
}

// ---------------- pack 3x W (128x128 fp32) into MFMA B-fragment order, fp16, one launch -----
__global__ __launch_bounds__(256) void k_packW3(const float* __restrict__ W2, const float* __restrict__ W3,
                                                const float* __restrict__ W4, f16* __restrict__ Wp) {
    int idx = blockIdx.x * 256 + threadIdx.x;   // 192 blocks x 256 = 49152 = 3 * 16384
    int which = idx >> 14;
    int r = idx & 16383;
    const float* W = (which == 0) ? W2 : (which == 1) ? W3 : W4;
    int j  = r & 7;
    int L  = (r >> 3) & 63;
    int ks = (r >> 9) & 3;
    int ct = r >> 11;
    int k = ks * 32 + (L >> 4) * 8 + j;
    int n = ct * 16 + (L & 15);
    Wp[idx] = (f16)W[k * HID + n];
}

// ---------------- pooling pass 1: per (graph, segment) partial sums, fp32, deterministic -----
__device__ __forceinline__ int lower_bound_batch(const int* __restrict__ batch, int val) {
    int lo = 0, hi = N_NODES;
    while (lo < hi) { int m = (lo + hi) >> 1; if (batch[m] < val) lo = m + 1; else hi = m; }
    return lo;
}

__global__ __launch_bounds__(128) void k_pool1(const f16* __restrict__ h, const int* __restrict__ batch,
                                               float* __restrict__ partials) {
    int g = blockIdx.x / POOL_SEG;
    int s = blockIdx.x % POOL_SEG;
    int f = threadIdx.x;
    int beg = lower_bound_batch(batch, g);
    int end = lower_bound_batch(batch, g + 1);
    int len = end - beg;
    int sb = beg + (int)(((long long)len * s) / POOL_SEG);
    int se = beg + (int)(((long long)len * (s + 1)) / POOL_SEG);
    float acc = 0.0f;
    for (int i = sb; i < se; ++i) acc += (float)h[i * HID + f];
    partials[(size_t)blockIdx.x * HID + f] = acc;
}

// ---------------- pooling pass 2 + head fused ---------------
__global__ __launch_bounds__(128) void k_pool2h(const float* __restrict__ partials,
                                                const int* __restrict__ batch,
                                                const float* __restrict__ Wl, const float* __restrict__ bl,
                                                float* __restrict__ out) {
    __shared__ float sp[HID];
    int g = blockIdx.x;
    int f = threadIdx.x;
    float acc = 0.0f;
#pragma unroll
    for (int s = 0; s < POOL_SEG; ++s)
        acc += partials[(size_t)(g * POOL_SEG + s) * HID + f];
    int beg = lower_bound_batch(batch, g);
    int end = lower_bound_batch(batch, g + 1);
    sp[f] = acc / fmaxf((float)(end - beg), 1.0f);
    __syncthreads();
    if (f < N_CLS) {
        float v = bl[f];
        for (int k = 0; k < HID; ++k) v = fmaf(sp[k], Wl[k * N_CLS + f], v);
        out[g * N_CLS + f] = 1.0f / (1.0f + expf(-v));
    }
}

extern "C" void kernel_launch(void* const* d_in, const int* in_sizes, int n_in,
                              void* d_out, int out_size, void* d_ws, size_t ws_size,
                              hipStream_t stream) {
    const float* x     = (const float*)d_in[0];
    const int*   ei    = (const int*)d_in[1];
    const int*   batch = (const int*)d_in[2];
    const float* W1 = (const float*)d_in[3];  const float* b1 = (const float*)d_in[4];
    const float* W2 = (const float*)d_in[5];  const float* b2 = (const float*)d_in[6];
    const float* W3 = (const float*)d_in[7];  const float* b3 = (const float*)d_in[8];
    const float* W4 = (const float*)d_in[9];  const float* b4 = (const float*)d_in[10];
    const float* Wl = (const float*)d_in[11]; const float* bl = (const float*)d_in[12];
    float* out = (float*)d_out;

    const size_t EPAD = (size_t)N_EDGES + (size_t)N_NODES * 16;   // padded edge capacity

    char* p = (char*)d_ws;
    auto alloc = [&](size_t bytes) { char* r = p; p += (bytes + 255) & ~(size_t)255; return (void*)r; };
    int*      C       = (int*)     alloc((size_t)NCHUNK * NBUK * 4);
    int*      Off     = (int*)     alloc((size_t)NCHUNK * NBUK * 4);
    int*      bbase   = (int*)     alloc((size_t)(NBUK + 1) * 4);
    int*      padTot  = (int*)     alloc((size_t)NBUK * 4);
    int*      padBase = (int*)     alloc((size_t)(NBUK + 1) * 4);
    int*      binCnt  = (int*)     alloc((size_t)NBIN * NBUK * 4);
    int*      binOff  = (int*)     alloc((size_t)NBIN * NBUK * 4);
    int*      order   = (int*)     alloc((size_t)N_NODES * 4);
    unsigned* bkt     = (unsigned*)alloc((size_t)N_EDGES * 4);
    int*      deg     = (int*)     alloc((size_t)N_NODES * 4);
    int*      rowptrP = (int*)     alloc((size_t)(N_NODES + 1) * 4);
    float*    dinv    = (float*)   alloc((size_t)N_NODES * 4);
    unsigned* edges   = (unsigned*)alloc(EPAD * 4);
    unsigned* hA      = (unsigned*)alloc((size_t)N_NODES * HID);      // fp8 ping
    unsigned* hC      = (unsigned*)alloc((size_t)N_NODES * HID);      // fp8 pong
    f16*      h4      = (f16*)     alloc((size_t)N_NODES * HID * 2);  // fp16 final layer out
    float*    parts   = (float*)   alloc((size_t)N_GRAPH * POOL_SEG * HID * 4);
    f16*      Wp      = (f16*)     alloc((size_t)3 * HID * HID * 2);
    f16*      Wp2 = Wp;
    f16*      Wp3 = Wp + HID * HID;
    f16*      Wp4 = Wp + 2 * HID * HID;

    const int* srcv = ei;              // edge_index[0]
    const int* dstv = ei + N_EDGES;    // edge_index[1]

    // CSR build: bucketed, no global atomics, padded-to-16 rows, coef fused, degree-bin order
    k_bc     <<<NCHUNK, 256, 0, stream>>>(dstv, C);
    k_bscan  <<<1, 256, 0, stream>>>(C, Off, bbase);
    k_scatter<<<NCHUNK, 256, 0, stream>>>(srcv, dstv, Off, bbase, bkt);
    k_hist2  <<<NBUK, 256, 0, stream>>>(bkt, bbase, deg, dinv, padTot, binCnt);
    k_pscan  <<<1, 256, 0, stream>>>(padTot, padBase, rowptrP, binCnt, binOff);
    k_order  <<<NBUK, 256, 0, stream>>>(deg, binOff, order);
    k_local2 <<<NBUK, 256, 0, stream>>>(bkt, bbase, deg, dinv, padBase, rowptrP, edges);

    k_packW3<<<192, 256, 0, stream>>>(W2, W3, W4, Wp);

    // layer 1: fused wave-parallel Agg(x) + (Nx4)@(4x128) GEMM, fp8 out
    k_aggx1<<<N_NODES / 16, 256, 0, stream>>>((const float4*)x, rowptrP, edges, dinv, order, W1, b1, hA);

    // layers 2..4: fused Agg (fp8 gather, degree-balanced blocks) + MFMA GEMM (+bias, ReLU)
    const int fgrid = N_NODES / 16;   // 6250, 1024-thread blocks
    k_aggemm8<true ><<<fgrid, 1024, 0, stream>>>(hA, rowptrP, edges, dinv, order, Wp2, b2, hC);
    k_aggemm8<true ><<<fgrid, 1024, 0, stream>>>(hC, rowptrP, edges, dinv, order, Wp3, b3, hA);
    k_aggemm8<false><<<fgrid, 1024, 0, stream>>>(hA, rowptrP, edges, dinv, order, Wp4, b4, h4);

    k_pool1 <<<N_GRAPH * POOL_SEG, 128, 0, stream>>>(h4, batch, parts);
    k_pool2h<<<N_GRAPH, 128, 0, stream>>>(parts, batch, Wl, bl, out);
}

// Round 14
// 357.853 us; speedup vs baseline: 1.0305x; 1.0305x over previous
//
#include <hip/hip_runtime.h>
#include <hip/hip_fp8.h>
#include <math.h>

#define N_NODES 100000
#define N_EDGES 1600000
#define F_IN    4
#define HID     128
#define N_CLS   5
#define N_GRAPH 256
#define POOL_SEG 8

#define BSHIFT   9
#define BSIZE    512
#define NBUK     196            // ceil(100000 / 512)
#define NCHUNK   200
#define CHUNK    8000           // 200 * 8000 = 1.6M exactly

typedef _Float16 f16;
typedef _Float16 f16x2 __attribute__((ext_vector_type(2)));
typedef _Float16 f16x8 __attribute__((ext_vector_type(8)));
typedef float f32x4 __attribute__((ext_vector_type(4)));

// decode 4-byte edge record: [src:17 | coef-f16-positive:15]; record 0 == dummy (src 0, coef 0)
__device__ __forceinline__ float rec_coef(unsigned r) {
    return (float)__builtin_bit_cast(_Float16, (unsigned short)(r & 0x7FFFu));
}

__device__ __forceinline__ float2 fp8x2_to_f32x2(unsigned short raw) {
    __hip_fp8x2_e4m3 t;
    t.__x = raw;
    return static_cast<float2>(t);
}

// 8 fp8 values (uint2) -> fma into acc[0..7] with coefficient c
__device__ __forceinline__ void fma8(float c, uint2 v, float* acc) {
    float2 p0 = fp8x2_to_f32x2((unsigned short)(v.x & 0xFFFFu));
    float2 p1 = fp8x2_to_f32x2((unsigned short)(v.x >> 16));
    float2 p2 = fp8x2_to_f32x2((unsigned short)(v.y & 0xFFFFu));
    float2 p3 = fp8x2_to_f32x2((unsigned short)(v.y >> 16));
    acc[0] = fmaf(c, p0.x, acc[0]); acc[1] = fmaf(c, p0.y, acc[1]);
    acc[2] = fmaf(c, p1.x, acc[2]); acc[3] = fmaf(c, p1.y, acc[3]);
    acc[4] = fmaf(c, p2.x, acc[4]); acc[5] = fmaf(c, p2.y, acc[5]);
    acc[6] = fmaf(c, p3.x, acc[6]); acc[7] = fmaf(c, p3.y, acc[7]);
}

// ---------------- CSR build step 1: per-(chunk,bucket) counts via LDS histogram -------------
__global__ __launch_bounds__(256) void k_bc(const int* __restrict__ dst, int* __restrict__ C) {
    __shared__ int cnt[NBUK];
    int t = threadIdx.x;
    if (t < NBUK) cnt[t] = 0;
    __syncthreads();
    int base = blockIdx.x * CHUNK;
#pragma unroll
    for (int it = 0; it < 32; ++it) {
        int idx = it * 256 + t;
        if (idx < CHUNK) atomicAdd(&cnt[dst[base + idx] >> BSHIFT], 1);
    }
    __syncthreads();
    if (t < NBUK) C[blockIdx.x * NBUK + t] = cnt[t];
}

// ---------------- step 2: offsets. Off[c][b] = prefix over chunks; bbase = bucket bases -----
__global__ __launch_bounds__(256) void k_bscan(const int* __restrict__ C, int* __restrict__ Off,
                                               int* __restrict__ bbase) {
    __shared__ int s[256];
    int b = threadIdx.x;
    int tot = 0;
    if (b < NBUK) {
        for (int c = 0; c < NCHUNK; ++c) {
            Off[c * NBUK + b] = tot;
            tot += C[c * NBUK + b];
        }
    }
    s[b] = (b < NBUK) ? tot : 0;
    __syncthreads();
    for (int off = 1; off < 256; off <<= 1) {
        int v = (b >= off) ? s[b - off] : 0;
        __syncthreads();
        s[b] += v;
        __syncthreads();
    }
    if (b < NBUK) bbase[b] = s[b] - tot;   // exclusive
    if (b == 0) bbase[NBUK] = N_EDGES;
}

// ---------------- step 3: scatter packed records into bucket-grouped array ------------------
// record: (src:17)<<9 | (dst & 511)
__global__ __launch_bounds__(256) void k_scatter(const int* __restrict__ src, const int* __restrict__ dst,
                                                 const int* __restrict__ Off, const int* __restrict__ bbase,
                                                 unsigned* __restrict__ bkt) {
    __shared__ int cur[NBUK];
    int t = threadIdx.x;
    if (t < NBUK) cur[t] = bbase[t] + Off[blockIdx.x * NBUK + t];
    __syncthreads();
    int base = blockIdx.x * CHUNK;
#pragma unroll
    for (int it = 0; it < 32; ++it) {
        int idx = it * 256 + t;
        if (idx < CHUNK) {
            int s = src[base + idx], d = dst[base + idx];
            int b = d >> BSHIFT;
            int p = atomicAdd(&cur[b], 1);
            bkt[p] = ((unsigned)s << BSHIFT) | (unsigned)(d & (BSIZE - 1));
        }
    }
}

// ---------------- step 4: per-bucket degree hist -> deg, dinv, padded bucket total ----------
__global__ __launch_bounds__(256) void k_hist2(const unsigned* __restrict__ bkt,
                                               const int* __restrict__ bbase,
                                               int* __restrict__ deg, float* __restrict__ dinv,
                                               int* __restrict__ padTot) {
    __shared__ int hist[BSIZE];
    __shared__ int tot;
    int t = threadIdx.x, b = blockIdx.x;
    hist[t] = 0; hist[t + 256] = 0;
    if (t == 0) tot = 0;
    __syncthreads();
    int s0 = bbase[b], s1 = bbase[b + 1];
    for (int e = s0 + t; e < s1; e += 256) atomicAdd(&hist[bkt[e] & (BSIZE - 1)], 1);
    __syncthreads();
    int loc = 0;
#pragma unroll
    for (int h = 0; h < 2; ++h) {
        int l = t + h * 256;
        int node = b * BSIZE + l;
        int d = hist[l];
        if (node < N_NODES) {
            deg[node] = d;
            dinv[node] = rsqrtf((float)d + 1.0f);
        }
        loc += (d + 15) >> 4;
    }
    atomicAdd(&tot, loc);
    __syncthreads();
    if (t == 0) padTot[b] = tot << 4;
}

// ---------------- step 5: scan padded bucket totals -> padded bases ------------------------
__global__ __launch_bounds__(256) void k_pscan(const int* __restrict__ padTot, int* __restrict__ padBase,
                                               int* __restrict__ rowptrP) {
    __shared__ int s[256];
    int b = threadIdx.x;
    int v = (b < NBUK) ? padTot[b] : 0;
    s[b] = v;
    __syncthreads();
    for (int off = 1; off < 256; off <<= 1) {
        int u = (b >= off) ? s[b - off] : 0;
        __syncthreads();
        s[b] += u;
        __syncthreads();
    }
    if (b < NBUK) padBase[b] = s[b] - v;
    if (b == 0) {
        padBase[NBUK] = s[NBUK - 1];
        rowptrP[N_NODES] = s[NBUK - 1];
    }
}

// ---------------- step 6: per-bucket padded CSR + coef fused; dummy slots = record 0 --------
__global__ __launch_bounds__(256) void k_local2(const unsigned* __restrict__ bkt,
                                                const int* __restrict__ bbase,
                                                const int* __restrict__ deg,
                                                const float* __restrict__ dinv,
                                                const int* __restrict__ padBase,
                                                int* __restrict__ rowptrP,
                                                unsigned* __restrict__ edges) {
    __shared__ int sc[BSIZE];
    __shared__ int cur[BSIZE];
    __shared__ float dv[BSIZE];
    int t = threadIdx.x, b = blockIdx.x;
    int base = padBase[b];
    int n0 = b * BSIZE + t, n1 = n0 + 256;
    int d0 = (n0 < N_NODES) ? deg[n0] : 0;
    int d1 = (n1 < N_NODES) ? deg[n1] : 0;
    int p0 = ((d0 + 15) >> 4) << 4;
    int p1 = ((d1 + 15) >> 4) << 4;
    sc[t] = p0; sc[t + 256] = p1;
    dv[t] = (n0 < N_NODES) ? dinv[n0] : 0.f;
    dv[t + 256] = (n1 < N_NODES) ? dinv[n1] : 0.f;
    __syncthreads();
    for (int off = 1; off < BSIZE; off <<= 1) {
        int i0 = t, i1 = t + 256;
        int v0 = (i0 >= off) ? sc[i0 - off] : 0;
        int v1 = (i1 >= off) ? sc[i1 - off] : 0;
        __syncthreads();
        sc[i0] += v0; sc[i1] += v1;
        __syncthreads();
    }
    int off0 = base + sc[t] - p0;
    int off1 = base + sc[t + 256] - p1;
    if (n0 < N_NODES) rowptrP[n0] = off0;
    if (n1 < N_NODES) rowptrP[n1] = off1;
    cur[t] = off0; cur[t + 256] = off1;
    int padT = sc[BSIZE - 1];
    // init padded region to dummy (record 0 = src 0, coef 0)
    for (int i = base + t; i < base + padT; i += 256) edges[i] = 0;
    __syncthreads();
    int s0 = bbase[b], s1 = bbase[b + 1];
    for (int e = s0 + t; e < s1; e += 256) {
        unsigned r = bkt[e];
        int dl = (int)(r & (BSIZE - 1));
        int s = (int)(r >> BSHIFT);
        int p = atomicAdd(&cur[dl], 1);
        float c = dv[dl] * dinv[s];
        unsigned short cb = __builtin_bit_cast(unsigned short, (f16)c);
        edges[p] = ((unsigned)s << 15) | (unsigned)(cb & 0x7FFFu);
    }
}

// ---------------- FUSED layer 1: wave-parallel Agg(x) + (Nx4)@(4x128) GEMM, fp8 out ---------
// Block = 256 thr = 16 node-groups of 16 lanes. Edge lists padded to x16 -> no tail.
__global__ __launch_bounds__(256) void k_aggx1(const float4* __restrict__ x,
                                               const int* __restrict__ rowptrP,
                                               const unsigned* __restrict__ edges,
                                               const float* __restrict__ dinv,
                                               const float* __restrict__ W1, const float* __restrict__ b1,
                                               unsigned* __restrict__ hA) {
    __shared__ float4 sxa[16];
    __shared__ float sW[4 * HID];
    __shared__ float sb[HID];
    int t = threadIdx.x;
    sW[t] = W1[t];
    sW[t + 256] = W1[t + 256];
    if (t < HID) sb[t] = b1[t];
    int grp = t >> 4;             // 0..15 local node
    int l = t & 15;
    int node = blockIdx.x * 16 + grp;   // grid 6250 -> exact
    int beg = rowptrP[node], end = rowptrP[node + 1];
    float ax = 0.f, ay = 0.f, az = 0.f, aw = 0.f;
    for (int e = beg + l; e < end; e += 16) {
        unsigned r = edges[e];
        float c = rec_coef(r);
        float4 v = x[r >> 15];
        ax = fmaf(c, v.x, ax); ay = fmaf(c, v.y, ay);
        az = fmaf(c, v.z, az); aw = fmaf(c, v.w, aw);
    }
#pragma unroll
    for (int off = 1; off < 16; off <<= 1) {
        ax += __shfl_xor(ax, off, 64);
        ay += __shfl_xor(ay, off, 64);
        az += __shfl_xor(az, off, 64);
        aw += __shfl_xor(aw, off, 64);
    }
    if (l == 0) {
        float di = dinv[node];
        float c0 = di * di;
        float4 xv = x[node];
        sxa[grp] = make_float4(fmaf(c0, xv.x, ax), fmaf(c0, xv.y, ay),
                               fmaf(c0, xv.z, az), fmaf(c0, xv.w, aw));
    }
    __syncthreads();

    int node0 = blockIdx.x * 16;
#pragma unroll
    for (int it = 0; it < 2; ++it) {
        int id = it * 256 + t;       // 512 units = 16 nodes x 32 col-groups
        int n = id >> 5;
        int g = id & 31;
        float4 a = sxa[n];
        float c[4];
#pragma unroll
        for (int j = 0; j < 4; ++j) {
            int col = g * 4 + j;
            float v = sb[col];
            v = fmaf(a.x, sW[col],           v);
            v = fmaf(a.y, sW[HID + col],     v);
            v = fmaf(a.z, sW[2 * HID + col], v);
            v = fmaf(a.w, sW[3 * HID + col], v);
            c[j] = fmaxf(v, 0.0f);
        }
        unsigned lo = __hip_fp8x2_e4m3(make_float2(c[0], c[1])).__x;
        unsigned hi = __hip_fp8x2_e4m3(make_float2(c[2], c[3])).__x;
        hA[(node0 + n) * 32 + g] = lo | (hi << 16);
    }
}

// ---------------- FUSED layers 2..4: Agg (fp8, wave/node) -> LDS -> MFMA GEMM ---------------
// Block = 1024 thr = 16 waves = 16 nodes. W is prefetched into registers at kernel start
// (no wait), stored to LDS after the agg phase (latency fully hidden), so the serial GEMM
// phase reads B-fragments from LDS (ds_read_b128) instead of L2 -> shorter per-block tail.
template <bool FP8OUT>
__global__ __launch_bounds__(1024, 8) void k_aggemm8(const unsigned* __restrict__ h8,
                                                     const int* __restrict__ rowptrP,
                                                     const unsigned* __restrict__ edges,
                                                     const float* __restrict__ dinv,
                                                     const f16* __restrict__ Wp,
                                                     const float* __restrict__ bias,
                                                     void* __restrict__ outv) {
    __shared__ f16 S[16 * HID];        // 4 KB strip, rows XOR-swizzled at dword granularity
    __shared__ f16 sW[HID * HID];      // 32 KB: full B matrix in MFMA fragment order
    int wave = threadIdx.x >> 6;        // local node 0..15
    int lane = threadIdx.x & 63;
    int node0 = blockIdx.x * 16;
    int node = node0 + wave;
    int g = lane >> 4;
    int l = lane & 15;
    int beg = rowptrP[node], end = rowptrP[node + 1];
    const char* hp = (const char*)h8 + l * 8;

    // issue W prefetch (2 x 16B per thread); consumed after agg -> latency hidden
    uint4 w0 = ((const uint4*)Wp)[threadIdx.x];
    uint4 w1 = ((const uint4*)Wp)[threadIdx.x + 1024];

    float acc[8];
    {
        float di = dinv[node];
        float c0 = (g == 0) ? di * di : 0.0f;
        uint2 v = *(const uint2*)(hp + ((size_t)node << 7));
        float2 p0 = fp8x2_to_f32x2((unsigned short)(v.x & 0xFFFFu));
        float2 p1 = fp8x2_to_f32x2((unsigned short)(v.x >> 16));
        float2 p2 = fp8x2_to_f32x2((unsigned short)(v.y & 0xFFFFu));
        float2 p3 = fp8x2_to_f32x2((unsigned short)(v.y >> 16));
        acc[0] = c0 * p0.x; acc[1] = c0 * p0.y;
        acc[2] = c0 * p1.x; acc[3] = c0 * p1.y;
        acc[4] = c0 * p2.x; acc[5] = c0 * p2.y;
        acc[6] = c0 * p3.x; acc[7] = c0 * p3.y;
    }

    for (int e = beg; e < end; e += 16) {
        unsigned rec16 = edges[e + l];
#pragma unroll
        for (int i = 0; i < 4; ++i) {
            unsigned rec = __shfl(rec16, i * 4 + g, 64);
            float c = rec_coef(rec);
            uint2 v = *(const uint2*)(hp + ((rec >> 8) & 0xFFFFFF80u));
            fma8(c, v, acc);
        }
    }

#pragma unroll
    for (int j = 0; j < 8; ++j) {
        acc[j] += __shfl_xor(acc[j], 16, 64);
        acc[j] += __shfl_xor(acc[j], 32, 64);
    }
    if (lane < 16) {
        f16x8 o;
#pragma unroll
        for (int j = 0; j < 8; ++j) o[j] = (f16)acc[j];
        int dw = (l * 4) ^ ((wave & 7) << 2);       // dword offset within row, swizzled
        *(f16x8*)&S[wave * HID + dw * 2] = o;
    }
    // store prefetched W to LDS (waits the global loads here, after ~all agg work)
    ((uint4*)sW)[threadIdx.x] = w0;
    ((uint4*)sW)[threadIdx.x + 1024] = w1;
    __syncthreads();

    // GEMM phase: waves 0..7 each handle column tile t = wave; B from LDS
    if (wave < 8) {
        int t = wave;
        int m = lane & 15;
        int q = lane >> 4;
        f32x4 c4 = (f32x4){0.f, 0.f, 0.f, 0.f};
#pragma unroll
        for (int ks = 0; ks < 4; ++ks) {
            int dw = (ks * 16 + q * 4) ^ ((m & 7) << 2);
            f16x8 a = *(const f16x8*)&S[m * HID + dw * 2];
            f16x8 b = *(const f16x8*)&sW[((size_t)(t * 4 + ks) * 64 + lane) * 8];
            c4 = __builtin_amdgcn_mfma_f32_16x16x32_f16(a, b, c4, 0, 0, 0);
        }
        float bb = bias[t * 16 + m];
#pragma unroll
        for (int r = 0; r < 4; ++r) {
            float val = fmaxf(c4[r] + bb, 0.0f);
            int row = node0 + q * 4 + r;
            if constexpr (FP8OUT) {
                ((__hip_fp8_e4m3*)outv)[(size_t)row * HID + t * 16 + m] = __hip_fp8_e4m3(val);
            } else {
                ((f16*)outv)[(size_t)row * HID + t * 16 + m] = (f16)val;
            }
        }
    }
}

// ---------------- pack 3x W (128x128 fp32) into MFMA B-fragment order, fp16, one launch -----
__global__ __launch_bounds__(256) void k_packW3(const float* __restrict__ W2, const float* __restrict__ W3,
                                                const float* __restrict__ W4, f16* __restrict__ Wp) {
    int idx = blockIdx.x * 256 + threadIdx.x;   // 192 blocks x 256 = 49152 = 3 * 16384
    int which = idx >> 14;
    int r = idx & 16383;
    const float* W = (which == 0) ? W2 : (which == 1) ? W3 : W4;
    int j  = r & 7;
    int L  = (r >> 3) & 63;
    int ks = (r >> 9) & 3;
    int ct = r >> 11;
    int k = ks * 32 + (L >> 4) * 8 + j;
    int n = ct * 16 + (L & 15);
    Wp[idx] = (f16)W[k * HID + n];
}

// ---------------- pooling pass 1: per (graph, segment) partial sums, fp32, deterministic -----
__device__ __forceinline__ int lower_bound_batch(const int* __restrict__ batch, int val) {
    int lo = 0, hi = N_NODES;
    while (lo < hi) { int m = (lo + hi) >> 1; if (batch[m] < val) lo = m + 1; else hi = m; }
    return lo;
}

__global__ __launch_bounds__(128) void k_pool1(const f16* __restrict__ h, const int* __restrict__ batch,
                                               float* __restrict__ partials) {
    int g = blockIdx.x / POOL_SEG;
    int s = blockIdx.x % POOL_SEG;
    int f = threadIdx.x;
    int beg = lower_bound_batch(batch, g);
    int end = lower_bound_batch(batch, g + 1);
    int len = end - beg;
    int sb = beg + (int)(((long long)len * s) / POOL_SEG);
    int se = beg + (int)(((long long)len * (s + 1)) / POOL_SEG);
    float acc = 0.0f;
    for (int i = sb; i < se; ++i) acc += (float)h[i * HID + f];
    partials[(size_t)blockIdx.x * HID + f] = acc;
}

// ---------------- pooling pass 2 + head fused ---------------
__global__ __launch_bounds__(128) void k_pool2h(const float* __restrict__ partials,
                                                const int* __restrict__ batch,
                                                const float* __restrict__ Wl, const float* __restrict__ bl,
                                                float* __restrict__ out) {
    __shared__ float sp[HID];
    int g = blockIdx.x;
    int f = threadIdx.x;
    float acc = 0.0f;
#pragma unroll
    for (int s = 0; s < POOL_SEG; ++s)
        acc += partials[(size_t)(g * POOL_SEG + s) * HID + f];
    int beg = lower_bound_batch(batch, g);
    int end = lower_bound_batch(batch, g + 1);
    sp[f] = acc / fmaxf((float)(end - beg), 1.0f);
    __syncthreads();
    if (f < N_CLS) {
        float v = bl[f];
        for (int k = 0; k < HID; ++k) v = fmaf(sp[k], Wl[k * N_CLS + f], v);
        out[g * N_CLS + f] = 1.0f / (1.0f + expf(-v));
    }
}

extern "C" void kernel_launch(void* const* d_in, const int* in_sizes, int n_in,
                              void* d_out, int out_size, void* d_ws, size_t ws_size,
                              hipStream_t stream) {
    const float* x     = (const float*)d_in[0];
    const int*   ei    = (const int*)d_in[1];
    const int*   batch = (const int*)d_in[2];
    const float* W1 = (const float*)d_in[3];  const float* b1 = (const float*)d_in[4];
    const float* W2 = (const float*)d_in[5];  const float* b2 = (const float*)d_in[6];
    const float* W3 = (const float*)d_in[7];  const float* b3 = (const float*)d_in[8];
    const float* W4 = (const float*)d_in[9];  const float* b4 = (const float*)d_in[10];
    const float* Wl = (const float*)d_in[11]; const float* bl = (const float*)d_in[12];
    float* out = (float*)d_out;

    const size_t EPAD = (size_t)N_EDGES + (size_t)N_NODES * 16;   // padded edge capacity

    char* p = (char*)d_ws;
    auto alloc = [&](size_t bytes) { char* r = p; p += (bytes + 255) & ~(size_t)255; return (void*)r; };
    int*      C       = (int*)     alloc((size_t)NCHUNK * NBUK * 4);
    int*      Off     = (int*)     alloc((size_t)NCHUNK * NBUK * 4);
    int*      bbase   = (int*)     alloc((size_t)(NBUK + 1) * 4);
    int*      padTot  = (int*)     alloc((size_t)NBUK * 4);
    int*      padBase = (int*)     alloc((size_t)(NBUK + 1) * 4);
    unsigned* bkt     = (unsigned*)alloc((size_t)N_EDGES * 4);
    int*      deg     = (int*)     alloc((size_t)N_NODES * 4);
    int*      rowptrP = (int*)     alloc((size_t)(N_NODES + 1) * 4);
    float*    dinv    = (float*)   alloc((size_t)N_NODES * 4);
    unsigned* edges   = (unsigned*)alloc(EPAD * 4);
    unsigned* hA      = (unsigned*)alloc((size_t)N_NODES * HID);      // fp8 ping
    unsigned* hC      = (unsigned*)alloc((size_t)N_NODES * HID);      // fp8 pong
    f16*      h4      = (f16*)     alloc((size_t)N_NODES * HID * 2);  // fp16 final layer out
    float*    parts   = (float*)   alloc((size_t)N_GRAPH * POOL_SEG * HID * 4);
    f16*      Wp      = (f16*)     alloc((size_t)3 * HID * HID * 2);
    f16*      Wp2 = Wp;
    f16*      Wp3 = Wp + HID * HID;
    f16*      Wp4 = Wp + 2 * HID * HID;

    const int* srcv = ei;              // edge_index[0]
    const int* dstv = ei + N_EDGES;    // edge_index[1]

    // CSR build: bucketed, no global atomics, padded-to-16 rows, coef fused into scatter
    k_bc     <<<NCHUNK, 256, 0, stream>>>(dstv, C);
    k_bscan  <<<1, 256, 0, stream>>>(C, Off, bbase);
    k_scatter<<<NCHUNK, 256, 0, stream>>>(srcv, dstv, Off, bbase, bkt);
    k_hist2  <<<NBUK, 256, 0, stream>>>(bkt, bbase, deg, dinv, padTot);
    k_pscan  <<<1, 256, 0, stream>>>(padTot, padBase, rowptrP);
    k_local2 <<<NBUK, 256, 0, stream>>>(bkt, bbase, deg, dinv, padBase, rowptrP, edges);

    k_packW3<<<192, 256, 0, stream>>>(W2, W3, W4, Wp);

    // layer 1: fused wave-parallel Agg(x) + (Nx4)@(4x128) GEMM, fp8 out
    k_aggx1<<<N_NODES / 16, 256, 0, stream>>>((const float4*)x, rowptrP, edges, dinv, W1, b1, hA);

    // layers 2..4: fused Agg (fp8 gather, full TLP) + MFMA GEMM (+bias, ReLU), B in LDS
    const int fgrid = N_NODES / 16;   // 6250, 1024-thread blocks
    k_aggemm8<true ><<<fgrid, 1024, 0, stream>>>(hA, rowptrP, edges, dinv, Wp2, b2, hC);
    k_aggemm8<true ><<<fgrid, 1024, 0, stream>>>(hC, rowptrP, edges, dinv, Wp3, b3, hA);
    k_aggemm8<false><<<fgrid, 1024, 0, stream>>>(hA, rowptrP, edges, dinv, Wp4, b4, h4);

    k_pool1 <<<N_GRAPH * POOL_SEG, 128, 0, stream>>>(h4, batch, parts);
    k_pool2h<<<N_GRAPH, 128, 0, stream>>>(parts, batch, Wl, bl, out);
}